// Round 3
// baseline (266.147 us; speedup 1.0000x reference)
//
#include <hip/hip_runtime.h>

#define NB 16
#define NC 256
#define NH 64
#define NW 64
#define PATCH 9
#define TROWS 4
#define CHST (NH * NW)               // channel plane stride (floats)
#define BLOCK_THREADS 576            // 9 waves; wave w == di
#define NBUF 4                       // LDS ring slots (>= prefetch_dist + 2)
#define XTILE (TROWS * NW)           // 256 floats = 1 KB  (x: 4 rows)
#define YROWS 12                     // y rows r0-4 .. r0+7
#define YTILE (YROWS * NW)           // 768 floats = 3 KB
#define SLOT  (XTILE + YTILE)        // 1024 floats = 4 KB per ring slot

typedef float f4_vec __attribute__((ext_vector_type(4)));

// DPP 16-lane-row shifts; row boundaries == pixel-row boundaries, so the
// shifted-in zeros implement horizontal zero-padding of y for free.
__device__ __forceinline__ float from_prev_lane(float v) {  // lane l <- lane l-1
    return __int_as_float(__builtin_amdgcn_update_dpp(
        0, __float_as_int(v), 0x111, 0xF, 0xF, true));      // row_shr:1
}
__device__ __forceinline__ float from_next_lane(float v) {  // lane l <- lane l+1
    return __int_as_float(__builtin_amdgcn_update_dpp(
        0, __float_as_int(v), 0x101, 0xF, 0xF, true));      // row_shl:1
}

__device__ __forceinline__ void accum(float acc[PATCH][4], float4 xa, float4 ya) {
    float wnd[12];
    wnd[0]  = from_prev_lane(ya.x);  wnd[1]  = from_prev_lane(ya.y);
    wnd[2]  = from_prev_lane(ya.z);  wnd[3]  = from_prev_lane(ya.w);
    wnd[4]  = ya.x;                  wnd[5]  = ya.y;
    wnd[6]  = ya.z;                  wnd[7]  = ya.w;
    wnd[8]  = from_next_lane(ya.x);  wnd[9]  = from_next_lane(ya.y);
    wnd[10] = from_next_lane(ya.z);  wnd[11] = from_next_lane(ya.w);

    const float xs[4] = {xa.x, xa.y, xa.z, xa.w};
    #pragma unroll
    for (int dj = 0; dj < PATCH; ++dj)
        #pragma unroll
        for (int tt = 0; tt < 4; ++tt)
            acc[dj][tt] = fmaf(xs[tt], wnd[tt + dj], acc[dj][tt]);
}

// async global(per-lane addr) -> LDS(uniform base + lane*16), 16B per lane
__device__ __forceinline__ void g2l(const float* g, float* l) {
    __builtin_amdgcn_global_load_lds(
        (const __attribute__((address_space(1))) void*)g,
        (__attribute__((address_space(3))) void*)l, 16, 0, 0);
}

// compiler-fenced raw barrier: NO vmcnt(0) drain (that would kill the ring)
__device__ __forceinline__ void block_sync() {
    asm volatile("" ::: "memory");
    __builtin_amdgcn_s_barrier();
    asm volatile("" ::: "memory");
}

// out[b, di*9+dj, i, j] = (1/C) * sum_c x[b,c,i,j] * y[b,c,i+di-4, j+dj-4]
__global__ void __launch_bounds__(BLOCK_THREADS)
corr_kernel(const float* __restrict__ x, const float* __restrict__ y,
            float* __restrict__ out, const float* __restrict__ zpad)
{
    __shared__ float lds[NBUF * SLOT];   // 16 KB

    const int tid  = threadIdx.x;
    const int w    = tid >> 6;           // wave 0..8 == di
    const int ln   = tid & 63;
    const int prow = ln >> 4;            // row within 4-row tile
    const int j0   = (ln & 15) << 2;     // col base (floats)

    // 256 blocks = 16 b x 16 t; pin each b's 16 blocks to one XCD.
    const int n    = blockIdx.x;
    const int xcd  = n & 7;
    const int k    = n >> 3;             // 0..31
    const int b    = xcd + ((k >> 4) << 3);
    const int t    = k & 15;
    const int r0   = t * TROWS;
    const int i    = r0 + prow;          // output pixel row

    // ---- staging roles: waves 0..3 each issue ONE global_load_lds per c ----
    // wave 0: x rows r0..r0+3 -> slot[0..XTILE)
    // wave 1..3: y rows (r0-4)+4*(w-1) .. +3 -> slot[XTILE + (w-1)*256 ..)
    const float* gp  = nullptr;   // per-lane source, advanced by gstep per c
    long         gstep = 0;       // floats
    int          ldst = 0;        // uniform float-offset within slot
    if (w == 0) {
        gp    = x + ((size_t)(b * NC) * NH + (r0 + prow)) * NW + j0;
        gstep = CHST;
        ldst  = 0;
    } else if (w <= 3) {
        const int ry = r0 - 4 + (w - 1) * 4 + prow;        // global y row
        const bool v = (ry >= 0) && (ry < NH);
        gp    = v ? (y + ((size_t)(b * NC) * NH + ry) * NW + j0) : (zpad + j0);
        gstep = v ? (long)CHST : 0;                        // zpad: stride 0
        ldst  = XTILE + (w - 1) * 4 * NW;
    }

    // ---- compute-side LDS read offsets (within a slot) ----
    const int xoff = prow * NW + j0;                 // own x fragment
    const int yoff = XTILE + (prow + w) * NW + j0;   // local y row = prow+w (always in range)

    float acc[PATCH][4];
    #pragma unroll
    for (int dj = 0; dj < PATCH; ++dj)
        #pragma unroll
        for (int tt = 0; tt < 4; ++tt) acc[dj][tt] = 0.0f;

    // prologue: stage c=0,1 into slots 0,1
    if (w < 4) {
        g2l(gp, &lds[0 * SLOT + ldst]); gp += gstep;
        g2l(gp, &lds[1 * SLOT + ldst]); gp += gstep;
    }

    // region c: [issue stage(c+2) -> slot (c+2)%4] [vmcnt(2): own stage(c) done]
    //           [barrier: ALL stage(c) done]       [ds_read slot c%4, accum]
    // WAR safety: slot (c+2)%4 last read in region c-2, separated by barrier(c-1).
    #define REGION(RS, WS_, DO_ISSUE, VMC)                                  \
    {                                                                       \
        if (w < 4) {                                                        \
            if (DO_ISSUE) { g2l(gp, &lds[(WS_) * SLOT + ldst]); gp += gstep; } \
            asm volatile("s_waitcnt vmcnt(" #VMC ")" ::: "memory");         \
        }                                                                   \
        block_sync();                                                       \
        float4 xa = *(const float4*)&lds[(RS) * SLOT + xoff];               \
        float4 ya = *(const float4*)&lds[(RS) * SLOT + yoff];               \
        accum(acc, xa, ya);                                                 \
    }

    #pragma unroll 1
    for (int c = 0; c < NC - 4; c += 4) {   // regions 0..251, stages 2..253
        REGION(0, 2, 1, 2)
        REGION(1, 3, 1, 2)
        REGION(2, 0, 1, 2)
        REGION(3, 1, 1, 2)
    }
    // tail regions 252..255 (stages 254,255 then drain)
    REGION(0, 2, 1, 2)
    REGION(1, 3, 1, 2)
    REGION(2, 0, 0, 1)
    REGION(3, 1, 0, 0)
    #undef REGION

    // epilogue: scale + coalesced nontemporal float4 stores
    const float scale = 1.0f / (float)NC;
    float* op = out + (((size_t)b * (PATCH * PATCH) + w * PATCH) * NH + i) * NW + j0;
    #pragma unroll
    for (int dj = 0; dj < PATCH; ++dj) {
        f4_vec o;
        o.x = acc[dj][0] * scale; o.y = acc[dj][1] * scale;
        o.z = acc[dj][2] * scale; o.w = acc[dj][3] * scale;
        __builtin_nontemporal_store(o, (f4_vec*)(op + (size_t)dj * CHST));
    }
}

extern "C" void kernel_launch(void* const* d_in, const int* in_sizes, int n_in,
                              void* d_out, int out_size, void* d_ws, size_t ws_size,
                              hipStream_t stream)
{
    const float* x = (const float*)d_in[0];
    const float* y = (const float*)d_in[1];
    float* out = (float*)d_out;

    // zero page for out-of-range y rows (ws is re-poisoned every launch)
    hipMemsetAsync(d_ws, 0, 1024, stream);

    dim3 grid(NB * (NH / TROWS));       // 256 blocks = 1 per CU
    dim3 block(BLOCK_THREADS);          // 576 = 9 waves (wave == di)
    hipLaunchKernelGGL(corr_kernel, grid, block, 0, stream, x, y, out,
                       (const float*)d_ws);
}

// Round 9
// 180.985 us; speedup vs baseline: 1.4705x; 1.4705x over previous
//
#include <hip/hip_runtime.h>

#define NB 16
#define NC 256
#define NH 64
#define NW 64
#define PATCH 9
#define TROWS 4
#define CHST (NH * NW)               // channel plane stride (floats)
#define BLOCK_THREADS 576            // 9 waves; wave w == di
#define G 4                          // channels per barrier region
#define NREG (NC / G)                // 64 regions
#define NBUF 3                       // ring super-slots (prefetch dist 1 region)
#define XTILE (TROWS * NW)           // 256 floats (x: 4 rows)
#define YROWS 12                     // y rows r0-4 .. r0+7
#define YTILE (YROWS * NW)           // 768 floats
#define SLOT  (XTILE + YTILE)        // 1024 floats = 4 KB per channel
#define SSLOT (G * SLOT)             // 4096 floats = 16 KB per region

typedef float f4_vec __attribute__((ext_vector_type(4)));

// DPP 16-lane-row shifts; row boundaries == pixel-row boundaries, so the
// shifted-in zeros implement horizontal zero-padding of y for free.
__device__ __forceinline__ float from_prev_lane(float v) {  // lane l <- lane l-1
    return __int_as_float(__builtin_amdgcn_update_dpp(
        0, __float_as_int(v), 0x111, 0xF, 0xF, true));      // row_shr:1
}
__device__ __forceinline__ float from_next_lane(float v) {  // lane l <- lane l+1
    return __int_as_float(__builtin_amdgcn_update_dpp(
        0, __float_as_int(v), 0x101, 0xF, 0xF, true));      // row_shl:1
}

__device__ __forceinline__ void accum(float acc[PATCH][4], float4 xa, float4 ya) {
    float wnd[12];
    wnd[0]  = from_prev_lane(ya.x);  wnd[1]  = from_prev_lane(ya.y);
    wnd[2]  = from_prev_lane(ya.z);  wnd[3]  = from_prev_lane(ya.w);
    wnd[4]  = ya.x;                  wnd[5]  = ya.y;
    wnd[6]  = ya.z;                  wnd[7]  = ya.w;
    wnd[8]  = from_next_lane(ya.x);  wnd[9]  = from_next_lane(ya.y);
    wnd[10] = from_next_lane(ya.z);  wnd[11] = from_next_lane(ya.w);

    const float xs[4] = {xa.x, xa.y, xa.z, xa.w};
    #pragma unroll
    for (int dj = 0; dj < PATCH; ++dj)
        #pragma unroll
        for (int tt = 0; tt < 4; ++tt)
            acc[dj][tt] = fmaf(xs[tt], wnd[tt + dj], acc[dj][tt]);
}

// async global(per-lane addr) -> LDS(uniform base + lane*16), 16B per lane
__device__ __forceinline__ void g2l(const float* g, float* l) {
    __builtin_amdgcn_global_load_lds(
        (const __attribute__((address_space(1))) void*)g,
        (__attribute__((address_space(3))) void*)l, 16, 0, 0);
}

// Counted barrier: drain DS reads (lgkmcnt) before s_barrier so a wave can
// never pass the barrier with slot reads still in the LDS pipeline (the WAR
// race vs next-next-region global_load_lds writes). sched_barrier(0) pins
// the ordering against hipcc migrating ds_reads/FMAs across the inline asm
// (rule: "memory" clobber does not order register-only ops). NO vmcnt drain
// here — staging waves keep their counted vmcnt(4) pipeline.
__device__ __forceinline__ void block_sync() {
    __builtin_amdgcn_sched_barrier(0);
    asm volatile("s_waitcnt lgkmcnt(0)" ::: "memory");
    __builtin_amdgcn_s_barrier();
    __builtin_amdgcn_sched_barrier(0);
}

// out[b, di*9+dj, i, j] = (1/C) * sum_c x[b,c,i,j] * y[b,c,i+di-4, j+dj-4]
__global__ void __launch_bounds__(BLOCK_THREADS)
corr_kernel(const float* __restrict__ x, const float* __restrict__ y,
            float* __restrict__ out, const float* __restrict__ zpad)
{
    __shared__ float lds[NBUF * SSLOT];  // 48 KB

    const int tid  = threadIdx.x;
    const int w    = tid >> 6;           // wave 0..8 == di
    const int ln   = tid & 63;
    const int prow = ln >> 4;            // row within 4-row tile
    const int j0   = (ln & 15) << 2;     // col base (floats)

    // 256 blocks = 16 b x 16 t; pin each b's 16 blocks to one XCD.
    const int n    = blockIdx.x;
    const int xcd  = n & 7;
    const int k    = n >> 3;             // 0..31
    const int b    = xcd + ((k >> 4) << 3);
    const int t    = k & 15;
    const int r0   = t * TROWS;
    const int i    = r0 + prow;          // output pixel row

    // staging roles: waves 0..3 each issue G gload_lds per region
    // wave 0: x rows r0..r0+3 -> [0..XTILE); waves 1..3: y row-quads
    const float* gp  = nullptr;
    long         gstep = 0;              // floats per channel
    int          ldst = 0;               // uniform float-offset within SLOT
    if (w == 0) {
        gp    = x + ((size_t)(b * NC) * NH + (r0 + prow)) * NW + j0;
        gstep = CHST;
        ldst  = 0;
    } else if (w <= 3) {
        const int ry = r0 - 4 + (w - 1) * 4 + prow;        // global y row
        const bool v = (ry >= 0) && (ry < NH);
        gp    = v ? (y + ((size_t)(b * NC) * NH + ry) * NW + j0) : (zpad + j0);
        gstep = v ? (long)CHST : 0;                        // zpad: stride 0
        ldst  = XTILE + (w - 1) * 4 * NW;
    }

    // compute-side LDS read offsets (within a SLOT)
    const int xoff = prow * NW + j0;                 // own x fragment
    const int yoff = XTILE + (prow + w) * NW + j0;   // local y row = prow+w

    float acc[PATCH][4];
    #pragma unroll
    for (int dj = 0; dj < PATCH; ++dj)
        #pragma unroll
        for (int tt = 0; tt < 4; ++tt) acc[dj][tt] = 0.0f;

    // prologue: stage channels 0..G-1 into super-slot 0
    if (w < 4) {
        #pragma unroll
        for (int u = 0; u < G; ++u) {
            g2l(gp, &lds[0 * SSLOT + u * SLOT + ldst]);
            gp += gstep;
        }
    }

    // region r: [issue G loads -> super-slot sw] [vmcnt(G): slot sr landed]
    //           [lgkm-drain + barrier] [compute G channels from slot sr]
    // WAR: slot sw = (r+1)%3 last read in region r-2; those reads are drained
    // (lgkmcnt 0) before barrier r-1, and the writes are issued after it.
    int sr = 0, sw = 1;
    #pragma unroll 1
    for (int r = 0; r < NREG; ++r) {
        if (w < 4) {
            if (r < NREG - 1) {
                float* db = &lds[sw * SSLOT + ldst];
                #pragma unroll
                for (int u = 0; u < G; ++u) { g2l(gp, db + u * SLOT); gp += gstep; }
                asm volatile("s_waitcnt vmcnt(4)" ::: "memory");
            } else {
                asm volatile("s_waitcnt vmcnt(0)" ::: "memory");
            }
            __builtin_amdgcn_sched_barrier(0);
        }
        block_sync();

        const float* sb = &lds[sr * SSLOT];
        #pragma unroll
        for (int u = 0; u < G; ++u) {
            float4 xa = *(const float4*)(sb + u * SLOT + xoff);
            float4 ya = *(const float4*)(sb + u * SLOT + yoff);
            accum(acc, xa, ya);
        }

        sr = sw;
        sw = (sw == NBUF - 1) ? 0 : sw + 1;
    }

    // epilogue: scale + coalesced nontemporal float4 stores
    const float scale = 1.0f / (float)NC;
    float* op = out + (((size_t)b * (PATCH * PATCH) + w * PATCH) * NH + i) * NW + j0;
    #pragma unroll
    for (int dj = 0; dj < PATCH; ++dj) {
        f4_vec o;
        o.x = acc[dj][0] * scale; o.y = acc[dj][1] * scale;
        o.z = acc[dj][2] * scale; o.w = acc[dj][3] * scale;
        __builtin_nontemporal_store(o, (f4_vec*)(op + (size_t)dj * CHST));
    }
}

extern "C" void kernel_launch(void* const* d_in, const int* in_sizes, int n_in,
                              void* d_out, int out_size, void* d_ws, size_t ws_size,
                              hipStream_t stream)
{
    const float* x = (const float*)d_in[0];
    const float* y = (const float*)d_in[1];
    float* out = (float*)d_out;

    // zero page for out-of-range y rows (ws is re-poisoned every launch)
    hipMemsetAsync(d_ws, 0, 1024, stream);

    dim3 grid(NB * (NH / TROWS));       // 256 blocks = 1 per CU
    dim3 block(BLOCK_THREADS);          // 576 = 9 waves (wave == di)
    hipLaunchKernelGGL(corr_kernel, grid, block, 0, stream, x, y, out,
                       (const float*)d_ws);
}

// Round 10
// 171.144 us; speedup vs baseline: 1.5551x; 1.0575x over previous
//
#include <hip/hip_runtime.h>

#define NB 16
#define NC 256
#define NH 64
#define NW 64
#define PATCH 9
#define TROWS 4
#define CHST (NH * NW)               // channel plane stride (floats)
#define BLOCK_THREADS 576            // 9 waves; wave w == di
#define G 8                          // channels per barrier region
#define NREG (NC / G)                // 32 regions
#define NBUF 3                       // ring super-slots (prefetch dist 1 region)
#define XTILE (TROWS * NW)           // 256 floats (x: 4 rows)
#define YROWS 12                     // y rows r0-4 .. r0+7
#define YTILE (YROWS * NW)           // 768 floats
#define SLOT  (XTILE + YTILE)        // 1024 floats = 4 KB per channel
#define SSLOT (G * SLOT)             // 8192 floats = 32 KB per region

typedef float f4_vec __attribute__((ext_vector_type(4)));

// DPP 16-lane-row shifts; row boundaries == pixel-row boundaries, so the
// shifted-in zeros implement horizontal zero-padding of y for free.
__device__ __forceinline__ float from_prev_lane(float v) {  // lane l <- lane l-1
    return __int_as_float(__builtin_amdgcn_update_dpp(
        0, __float_as_int(v), 0x111, 0xF, 0xF, true));      // row_shr:1
}
__device__ __forceinline__ float from_next_lane(float v) {  // lane l <- lane l+1
    return __int_as_float(__builtin_amdgcn_update_dpp(
        0, __float_as_int(v), 0x101, 0xF, 0xF, true));      // row_shl:1
}

__device__ __forceinline__ void accum(float acc[PATCH][4], float4 xa, float4 ya) {
    float wnd[12];
    wnd[0]  = from_prev_lane(ya.x);  wnd[1]  = from_prev_lane(ya.y);
    wnd[2]  = from_prev_lane(ya.z);  wnd[3]  = from_prev_lane(ya.w);
    wnd[4]  = ya.x;                  wnd[5]  = ya.y;
    wnd[6]  = ya.z;                  wnd[7]  = ya.w;
    wnd[8]  = from_next_lane(ya.x);  wnd[9]  = from_next_lane(ya.y);
    wnd[10] = from_next_lane(ya.z);  wnd[11] = from_next_lane(ya.w);

    const float xs[4] = {xa.x, xa.y, xa.z, xa.w};
    #pragma unroll
    for (int dj = 0; dj < PATCH; ++dj)
        #pragma unroll
        for (int tt = 0; tt < 4; ++tt)
            acc[dj][tt] = fmaf(xs[tt], wnd[tt + dj], acc[dj][tt]);
}

// async global(per-lane addr) -> LDS(uniform base + lane*16), 16B per lane
__device__ __forceinline__ void g2l(const float* g, float* l) {
    __builtin_amdgcn_global_load_lds(
        (const __attribute__((address_space(1))) void*)g,
        (__attribute__((address_space(3))) void*)l, 16, 0, 0);
}

// Counted barrier: drain DS reads (lgkmcnt) before s_barrier so a wave can
// never pass the barrier with slot reads still in the LDS pipeline (the WAR
// race vs next-next-region global_load_lds writes). sched_barrier(0) pins
// the ordering against hipcc migrating ds_reads/FMAs across the inline asm
// (rule: "memory" clobber does not order register-only ops). NO vmcnt drain
// here — staging waves keep their counted vmcnt(G) pipeline.
__device__ __forceinline__ void block_sync() {
    __builtin_amdgcn_sched_barrier(0);
    asm volatile("s_waitcnt lgkmcnt(0)" ::: "memory");
    __builtin_amdgcn_s_barrier();
    __builtin_amdgcn_sched_barrier(0);
}

// out[b, di*9+dj, i, j] = (1/C) * sum_c x[b,c,i,j] * y[b,c,i+di-4, j+dj-4]
__global__ void __launch_bounds__(BLOCK_THREADS)
corr_kernel(const float* __restrict__ x, const float* __restrict__ y,
            float* __restrict__ out, const float* __restrict__ zpad)
{
    __shared__ float lds[NBUF * SSLOT];  // 96 KB

    const int tid  = threadIdx.x;
    const int w    = tid >> 6;           // wave 0..8 == di
    const int ln   = tid & 63;
    const int prow = ln >> 4;            // row within 4-row tile
    const int j0   = (ln & 15) << 2;     // col base (floats)

    // 256 blocks = 16 b x 16 t; pin each b's 16 blocks to one XCD.
    const int n    = blockIdx.x;
    const int xcd  = n & 7;
    const int k    = n >> 3;             // 0..31
    const int b    = xcd + ((k >> 4) << 3);
    const int t    = k & 15;
    const int r0   = t * TROWS;
    const int i    = r0 + prow;          // output pixel row

    // staging roles: waves 0..3 each issue G gload_lds per region
    // wave 0: x rows r0..r0+3 -> [0..XTILE); waves 1..3: y row-quads
    const float* gp  = nullptr;
    long         gstep = 0;              // floats per channel
    int          ldst = 0;               // uniform float-offset within SLOT
    if (w == 0) {
        gp    = x + ((size_t)(b * NC) * NH + (r0 + prow)) * NW + j0;
        gstep = CHST;
        ldst  = 0;
    } else if (w <= 3) {
        const int ry = r0 - 4 + (w - 1) * 4 + prow;        // global y row
        const bool v = (ry >= 0) && (ry < NH);
        gp    = v ? (y + ((size_t)(b * NC) * NH + ry) * NW + j0) : (zpad + j0);
        gstep = v ? (long)CHST : 0;                        // zpad: stride 0
        ldst  = XTILE + (w - 1) * 4 * NW;
    }

    // compute-side LDS read offsets (within a SLOT)
    const int xoff = prow * NW + j0;                 // own x fragment
    const int yoff = XTILE + (prow + w) * NW + j0;   // local y row = prow+w

    float acc[PATCH][4];
    #pragma unroll
    for (int dj = 0; dj < PATCH; ++dj)
        #pragma unroll
        for (int tt = 0; tt < 4; ++tt) acc[dj][tt] = 0.0f;

    // prologue: stage channels 0..G-1 into super-slot 0
    if (w < 4) {
        #pragma unroll
        for (int u = 0; u < G; ++u) {
            g2l(gp, &lds[0 * SSLOT + u * SLOT + ldst]);
            gp += gstep;
        }
    }

    // region r: [issue G loads -> super-slot sw] [vmcnt(G): slot sr landed]
    //           [lgkm-drain + barrier] [compute G channels from slot sr]
    // WAR: slot sw = (r+1)%3 last read in region r-2; those reads are drained
    // (lgkmcnt 0) before barrier r-1, and the writes are issued after it.
    int sr = 0, sw = 1;
    #pragma unroll 1
    for (int r = 0; r < NREG; ++r) {
        if (w < 4) {
            if (r < NREG - 1) {
                float* db = &lds[sw * SSLOT + ldst];
                #pragma unroll
                for (int u = 0; u < G; ++u) { g2l(gp, db + u * SLOT); gp += gstep; }
                asm volatile("s_waitcnt vmcnt(8)" ::: "memory");   // = vmcnt(G)
            } else {
                asm volatile("s_waitcnt vmcnt(0)" ::: "memory");
            }
            __builtin_amdgcn_sched_barrier(0);
        }
        block_sync();

        const float* sb = &lds[sr * SSLOT];
        #pragma unroll
        for (int u = 0; u < G; ++u) {
            float4 xa = *(const float4*)(sb + u * SLOT + xoff);
            float4 ya = *(const float4*)(sb + u * SLOT + yoff);
            accum(acc, xa, ya);
        }

        sr = sw;
        sw = (sw == NBUF - 1) ? 0 : sw + 1;
    }

    // epilogue: scale + coalesced nontemporal float4 stores
    const float scale = 1.0f / (float)NC;
    float* op = out + (((size_t)b * (PATCH * PATCH) + w * PATCH) * NH + i) * NW + j0;
    #pragma unroll
    for (int dj = 0; dj < PATCH; ++dj) {
        f4_vec o;
        o.x = acc[dj][0] * scale; o.y = acc[dj][1] * scale;
        o.z = acc[dj][2] * scale; o.w = acc[dj][3] * scale;
        __builtin_nontemporal_store(o, (f4_vec*)(op + (size_t)dj * CHST));
    }
}

extern "C" void kernel_launch(void* const* d_in, const int* in_sizes, int n_in,
                              void* d_out, int out_size, void* d_ws, size_t ws_size,
                              hipStream_t stream)
{
    const float* x = (const float*)d_in[0];
    const float* y = (const float*)d_in[1];
    float* out = (float*)d_out;

    // zero page for out-of-range y rows (ws is re-poisoned every launch)
    hipMemsetAsync(d_ws, 0, 1024, stream);

    dim3 grid(NB * (NH / TROWS));       // 256 blocks = 1 per CU
    dim3 block(BLOCK_THREADS);          // 576 = 9 waves (wave == di)
    hipLaunchKernelGGL(corr_kernel, grid, block, 0, stream, x, y, out,
                       (const float*)d_ws);
}

// Round 11
// 168.964 us; speedup vs baseline: 1.5752x; 1.0129x over previous
//
#include <hip/hip_runtime.h>

#define NB 16
#define NC 256
#define NH 64
#define NW 64
#define PATCH 9
#define TROWS 4
#define CHST (NH * NW)               // channel plane stride (floats)
#define BLOCK_THREADS 576            // 9 waves; wave w == di
#define G 8                          // channels per barrier region
#define NREG (NC / G)                // 32 regions
#define NBUF 3                       // ring super-slots (prefetch dist 1 region)
#define XTILE (TROWS * NW)           // 256 floats (x: 4 rows)
#define YROWS 12                     // y rows r0-4 .. r0+7
#define YTILE (YROWS * NW)           // 768 floats
#define SLOT  (XTILE + YTILE)        // 1024 floats = 4 KB per channel
#define SSLOT (G * SLOT)             // 8192 floats = 32 KB per region

typedef float f4_vec __attribute__((ext_vector_type(4)));

// DPP 16-lane-row shifts; row boundaries == pixel-row boundaries, so the
// shifted-in zeros implement horizontal zero-padding of y for free.
__device__ __forceinline__ float from_prev_lane(float v) {  // lane l <- lane l-1
    return __int_as_float(__builtin_amdgcn_update_dpp(
        0, __float_as_int(v), 0x111, 0xF, 0xF, true));      // row_shr:1
}
__device__ __forceinline__ float from_next_lane(float v) {  // lane l <- lane l+1
    return __int_as_float(__builtin_amdgcn_update_dpp(
        0, __float_as_int(v), 0x101, 0xF, 0xF, true));      // row_shl:1
}

__device__ __forceinline__ void accum(float acc[PATCH][4], float4 xa, float4 ya) {
    float wnd[12];
    wnd[0]  = from_prev_lane(ya.x);  wnd[1]  = from_prev_lane(ya.y);
    wnd[2]  = from_prev_lane(ya.z);  wnd[3]  = from_prev_lane(ya.w);
    wnd[4]  = ya.x;                  wnd[5]  = ya.y;
    wnd[6]  = ya.z;                  wnd[7]  = ya.w;
    wnd[8]  = from_next_lane(ya.x);  wnd[9]  = from_next_lane(ya.y);
    wnd[10] = from_next_lane(ya.z);  wnd[11] = from_next_lane(ya.w);

    const float xs[4] = {xa.x, xa.y, xa.z, xa.w};
    #pragma unroll
    for (int dj = 0; dj < PATCH; ++dj)
        #pragma unroll
        for (int tt = 0; tt < 4; ++tt)
            acc[dj][tt] = fmaf(xs[tt], wnd[tt + dj], acc[dj][tt]);
}

// async global(per-lane addr) -> LDS(uniform base + lane*16), 16B per lane
__device__ __forceinline__ void g2l(const float* g, float* l) {
    __builtin_amdgcn_global_load_lds(
        (const __attribute__((address_space(1))) void*)g,
        (__attribute__((address_space(3))) void*)l, 16, 0, 0);
}

// Counted barrier: drain DS reads (lgkmcnt) before s_barrier so a wave can
// never pass the barrier with slot reads still in the LDS pipeline (the WAR
// race vs next-next-region global_load_lds writes). sched_barrier(0) pins
// the ordering against hipcc migrating ds_reads/FMAs across the inline asm
// (rule: "memory" clobber does not order register-only ops). NO vmcnt drain
// here — staging waves keep their counted vmcnt(G) pipeline.
__device__ __forceinline__ void block_sync() {
    __builtin_amdgcn_sched_barrier(0);
    asm volatile("s_waitcnt lgkmcnt(0)" ::: "memory");
    __builtin_amdgcn_s_barrier();
    __builtin_amdgcn_sched_barrier(0);
}

// out[b, di*9+dj, i, j] = (1/C) * sum_c x[b,c,i,j] * y[b,c,i+di-4, j+dj-4]
__global__ void __launch_bounds__(BLOCK_THREADS)
corr_kernel(const float* __restrict__ x, const float* __restrict__ y,
            float* __restrict__ out, const float* __restrict__ zpad)
{
    __shared__ float lds[NBUF * SSLOT];  // 96 KB

    const int tid  = threadIdx.x;
    const int w    = tid >> 6;           // wave 0..8 == di
    const int ln   = tid & 63;
    const int prow = ln >> 4;            // row within 4-row tile
    const int j0   = (ln & 15) << 2;     // col base (floats)

    // 256 blocks = 16 b x 16 t; pin each b's 16 blocks to one XCD.
    const int n    = blockIdx.x;
    const int xcd  = n & 7;
    const int k    = n >> 3;             // 0..31
    const int b    = xcd + ((k >> 4) << 3);
    const int t    = k & 15;
    const int r0   = t * TROWS;
    const int i    = r0 + prow;          // output pixel row

    // staging roles: waves 0..3 each issue G gload_lds per region
    // wave 0: x rows r0..r0+3 -> [0..XTILE); waves 1..3: y row-quads
    const float* gp  = nullptr;
    long         gstep = 0;              // floats per channel
    int          ldst = 0;               // uniform float-offset within SLOT
    if (w == 0) {
        gp    = x + ((size_t)(b * NC) * NH + (r0 + prow)) * NW + j0;
        gstep = CHST;
        ldst  = 0;
    } else if (w <= 3) {
        const int ry = r0 - 4 + (w - 1) * 4 + prow;        // global y row
        const bool v = (ry >= 0) && (ry < NH);
        gp    = v ? (y + ((size_t)(b * NC) * NH + ry) * NW + j0) : (zpad + j0);
        gstep = v ? (long)CHST : 0;                        // zpad: stride 0
        ldst  = XTILE + (w - 1) * 4 * NW;
    }

    // compute-side LDS read offsets (within a SLOT)
    const int xoff = prow * NW + j0;                 // own x fragment
    const int yoff = XTILE + (prow + w) * NW + j0;   // local y row = prow+w

    float acc[PATCH][4];
    #pragma unroll
    for (int dj = 0; dj < PATCH; ++dj)
        #pragma unroll
        for (int tt = 0; tt < 4; ++tt) acc[dj][tt] = 0.0f;

    // prologue: stage channels 0..G-1 into super-slot 0
    if (w < 4) {
        #pragma unroll
        for (int u = 0; u < G; ++u) {
            g2l(gp, &lds[0 * SSLOT + u * SLOT + ldst]);
            gp += gstep;
        }
    }

    // region r: [issue G loads -> super-slot sw] [vmcnt(G): slot sr landed]
    //           [lgkm-drain + barrier] [compute G channels from slot sr,
    //            depth-2 REGISTER pipeline over the LDS reads so the LDS
    //            pipe (reads for u+2) overlaps the VALU phase (compute u)
    //            instead of phase-serializing after each barrier]
    // WAR: slot sw = (r+1)%3 last read in region r-2; those reads are drained
    // (lgkmcnt 0) before barrier r-1, and the writes are issued after it.
    int sr = 0, sw = 1;
    #pragma unroll 1
    for (int r = 0; r < NREG; ++r) {
        if (w < 4) {
            if (r < NREG - 1) {
                float* db = &lds[sw * SSLOT + ldst];
                #pragma unroll
                for (int u = 0; u < G; ++u) { g2l(gp, db + u * SLOT); gp += gstep; }
                asm volatile("s_waitcnt vmcnt(8)" ::: "memory");   // = vmcnt(G)
            } else {
                asm volatile("s_waitcnt vmcnt(0)" ::: "memory");
            }
            __builtin_amdgcn_sched_barrier(0);
        }
        block_sync();

        const float* sb = &lds[sr * SSLOT];
        // depth-2 register prefetch over channels within the region
        float4 xa0 = *(const float4*)(sb + 0 * SLOT + xoff);
        float4 ya0 = *(const float4*)(sb + 0 * SLOT + yoff);
        float4 xa1 = *(const float4*)(sb + 1 * SLOT + xoff);
        float4 ya1 = *(const float4*)(sb + 1 * SLOT + yoff);
        #pragma unroll
        for (int u = 0; u < G; ++u) {
            const float4 xc = xa0, yc = ya0;
            xa0 = xa1; ya0 = ya1;
            if (u + 2 < G) {
                xa1 = *(const float4*)(sb + (u + 2) * SLOT + xoff);
                ya1 = *(const float4*)(sb + (u + 2) * SLOT + yoff);
            }
            accum(acc, xc, yc);
        }

        sr = sw;
        sw = (sw == NBUF - 1) ? 0 : sw + 1;
    }

    // epilogue: scale + coalesced nontemporal float4 stores
    const float scale = 1.0f / (float)NC;
    float* op = out + (((size_t)b * (PATCH * PATCH) + w * PATCH) * NH + i) * NW + j0;
    #pragma unroll
    for (int dj = 0; dj < PATCH; ++dj) {
        f4_vec o;
        o.x = acc[dj][0] * scale; o.y = acc[dj][1] * scale;
        o.z = acc[dj][2] * scale; o.w = acc[dj][3] * scale;
        __builtin_nontemporal_store(o, (f4_vec*)(op + (size_t)dj * CHST));
    }
}

extern "C" void kernel_launch(void* const* d_in, const int* in_sizes, int n_in,
                              void* d_out, int out_size, void* d_ws, size_t ws_size,
                              hipStream_t stream)
{
    const float* x = (const float*)d_in[0];
    const float* y = (const float*)d_in[1];
    float* out = (float*)d_out;

    // zero page for out-of-range y rows (ws is re-poisoned every launch)
    hipMemsetAsync(d_ws, 0, 1024, stream);

    dim3 grid(NB * (NH / TROWS));       // 256 blocks = 1 per CU
    dim3 block(BLOCK_THREADS);          // 576 = 9 waves (wave == di)
    hipLaunchKernelGGL(corr_kernel, grid, block, 0, stream, x, y, out,
                       (const float*)d_ws);
}